// Round 12
// baseline (259.366 us; speedup 1.0000x reference)
//
#include <hip/hip_runtime.h>
#include <hip/hip_bf16.h>

typedef unsigned short u16;
typedef __attribute__((ext_vector_type(8))) short bf16x8;
typedef __attribute__((ext_vector_type(4))) float f32x4;

#define AS1 __attribute__((address_space(1)))
#define AS3 __attribute__((address_space(3)))

constexpr int Bc = 4, Sc = 2048, Dc = 1024, Hc = 16, DKc = 64;
constexpr size_t EDc = (size_t)Bc * Sc * Dc;   // 8388608
constexpr size_t WDc = (size_t)Dc * Dc;        // 1048576

__device__ __forceinline__ void g2l16(const void* g, void* l) {
  __builtin_amdgcn_global_load_lds((const AS1 unsigned int*)g,
                                   (AS3 unsigned int*)l, 16, 0, 0);
}

__device__ __forceinline__ u16 f2b(float f) {
  union { float f; unsigned u; } x; x.f = f;
  unsigned r = x.u + 0x7fffu + ((x.u >> 16) & 1u);
  return (u16)(r >> 16);
}

// packed f32x2 -> bf16x2 (low = a). gfx950 has v_cvt_pk_bf16_f32.
#if __has_builtin(__builtin_amdgcn_cvt_pk_bf16_f32)
typedef __attribute__((ext_vector_type(2))) __bf16 hbf2;
__device__ __forceinline__ unsigned f2b_pk(float a, float b) {
  union { hbf2 v; unsigned u; } x;
  x.v = __builtin_amdgcn_cvt_pk_bf16_f32(a, b);
  return x.u;
}
#else
__device__ __forceinline__ unsigned f2b_pk(float a, float b) {
  return (unsigned)f2b(a) | ((unsigned)f2b(b) << 16);
}
#endif

__device__ __forceinline__ float fast_exp2(float x) {
#if __has_builtin(__builtin_amdgcn_exp2f)
  return __builtin_amdgcn_exp2f(x);
#else
  return exp2f(x);
#endif
}

// ---------------------------------------------------------------------------
// Fused fp32->bf16 for all 5 inputs (dest regions contiguous in ws).
// ---------------------------------------------------------------------------
__global__ __launch_bounds__(256)
void cvt_all(const float* __restrict__ e, const float* __restrict__ wq,
             const float* __restrict__ wk, const float* __restrict__ wv,
             const float* __restrict__ wo, u16* __restrict__ dst) {
  int bx = blockIdx.x;
  const float* src;
  size_t doff;
  int chunk;
  if (bx < 4096) {
    src = e; doff = 0; chunk = bx;
  } else {
    int t = bx - 4096;
    int w = t >> 9;
    chunk = t & 511;
    src = (w == 0) ? wq : (w == 1) ? wk : (w == 2) ? wv : wo;
    doff = EDc + (size_t)w * WDc;
  }
  size_t i = ((size_t)chunk * 256 + threadIdx.x) * 8;
  float4 a = *(const float4*)(src + i);
  float4 b = *(const float4*)(src + i + 4);
  bf16x8 o;
  o[0] = (short)f2b(a.x); o[1] = (short)f2b(a.y);
  o[2] = (short)f2b(a.z); o[3] = (short)f2b(a.w);
  o[4] = (short)f2b(b.x); o[5] = (short)f2b(b.y);
  o[6] = (short)f2b(b.z); o[7] = (short)f2b(b.w);
  *(bf16x8*)(dst + doff + i) = o;
}

// ---------------------------------------------------------------------------
// Fused QKV GEMM. sect 0 = Q (0.125*log2e folded), 1 = K, 2 = V
// (operand-swapped -> contiguous VT stores, within-64-key permutation
// pos(k): [h|b|qq|r] -> [h|qq|b|r] matching attn's register-resident P).
// XCD swizzle: each XCD owns 8 consecutive m-panels.
// Round-12: STREAMED-B inner loop (natural VGPR demand ~115) combined with
// __launch_bounds__(256,3) (cap 170) -> 3 blocks/CU, m97-class occupancy.
// Round-5's spill came from bulk fragments (demand ~160) at this bracket;
// with demand 115 even a snap to the 128 bracket still fits (no spill).
// ---------------------------------------------------------------------------
__global__ __launch_bounds__(256, 3)
void gemm_qkv(const u16* __restrict__ X, const u16* __restrict__ Wq,
              const u16* __restrict__ Wk, const u16* __restrict__ Wv,
              u16* __restrict__ Qo, u16* __restrict__ Ko,
              u16* __restrict__ VTo) {
  constexpr int BM = 128, BK = 64, K = Dc, N = Dc;
  __shared__ u16 As[BM * BK];
  __shared__ u16 Bs[BM * BK];

  const int tid = threadIdx.x;
  const int wave = tid >> 6, lane = tid & 63;
  const int mr = lane & 15, quad = lane >> 4, mr7 = lane & 7;
  const int hwlin = blockIdx.y * 24 + blockIdx.x;        // 1536 blocks
  const int swz = (hwlin & 7) * 192 + (hwlin >> 3);      // bijective
  const int lx = swz % 24, ly = swz / 24;
  const int sect = lx >> 3;
  const int n0 = (lx & 7) * 128;
  const int m0 = ly * BM;
  const u16* W = (sect == 0) ? Wq : (sect == 1) ? Wk : Wv;
  const int wm = (wave >> 1) * 64, wn = (wave & 1) * 64;
  const int ldr = lane >> 3;
  const int ldc_sw = ((lane & 7) ^ (ldr & 7)) * 8;
  const bool vsec = (sect == 2);

  const f32x4 zero = {0.f, 0.f, 0.f, 0.f};
  f32x4 acc[4][4];
  #pragma unroll
  for (int i = 0; i < 4; i++)
    #pragma unroll
    for (int j = 0; j < 4; j++) acc[i][j] = zero;

  for (int k0 = 0; k0 < K; k0 += BK) {
    __syncthreads();
    #pragma unroll
    for (int i = 0; i < 4; i++) {
      int row = wave * 32 + i * 8;
      g2l16(X + (size_t)(m0 + row + ldr) * K + k0 + ldc_sw, As + row * BK);
      g2l16(W + (size_t)(n0 + row + ldr) * K + k0 + ldc_sw, Bs + row * BK);
    }
    __syncthreads();

    #pragma unroll
    for (int c = 0; c < 2; c++) {
      bf16x8 a[4];
      #pragma unroll
      for (int i = 0; i < 4; i++)
        a[i] = *(const bf16x8*)(As + (wm + i * 16 + mr) * BK +
                                (((c * 4 + quad) ^ mr7) * 8));
      #pragma unroll
      for (int j = 0; j < 4; j++) {
        bf16x8 b = *(const bf16x8*)(Bs + (wn + j * 16 + mr) * BK +
                                    (((c * 4 + quad) ^ mr7) * 8));
        if (vsec) {
          #pragma unroll
          for (int i = 0; i < 4; i++)
            acc[i][j] = __builtin_amdgcn_mfma_f32_16x16x32_bf16(
                b, a[i], acc[i][j], 0, 0, 0);   // D = Y^T tile
        } else {
          #pragma unroll
          for (int i = 0; i < 4; i++)
            acc[i][j] = __builtin_amdgcn_mfma_f32_16x16x32_bf16(
                a[i], b, acc[i][j], 0, 0, 0);
        }
      }
    }
  }

  if (vsec) {
    #pragma unroll
    for (int i = 0; i < 4; i++) {
      int s_glob = m0 + wm + i * 16 + mr;
      int bb = s_glob >> 11, s = s_glob & 2047;
      int sp = (s & ~63) | (s & 32) | ((s & 12) << 1) | ((s & 16) >> 2) |
               (s & 3);
      #pragma unroll
      for (int j = 0; j < 4; j++) {
        int nbase = n0 + wn + j * 16 + quad * 4;
        #pragma unroll
        for (int r = 0; r < 4; r++) {
          int n = nbase + r;
          int h = n >> 6, d = n & 63;
          VTo[((size_t)((bb * Hc + h) * DKc + d)) * Sc + sp] = f2b(acc[i][j][r]);
        }
      }
    }
  } else {
    const float scale = (sect == 0) ? 0.18033688f : 1.0f;
    u16* Y = (sect == 0) ? Qo : Ko;
    #pragma unroll
    for (int i = 0; i < 4; i++)
      #pragma unroll
      for (int j = 0; j < 4; j++)
        #pragma unroll
        for (int r = 0; r < 4; r++) {
          int m = m0 + wm + i * 16 + quad * 4 + r;
          int n = n0 + wn + j * 16 + mr;
          Y[(size_t)m * N + n] = f2b(acc[i][j][r] * scale);
        }
  }
}

// ---------------------------------------------------------------------------
// Output GEMM: out = ctx @ Wo.T, fp32 output. XCD swizzle.
// Round-12: streamed-B + (256,3) (see gemm_qkv comment).
// ---------------------------------------------------------------------------
__global__ __launch_bounds__(256, 3)
void gemm_out(const u16* __restrict__ X, const u16* __restrict__ W,
              float* __restrict__ Y, int M, int N, int K) {
  constexpr int BM = 128, BK = 64;
  __shared__ u16 As[BM * BK];
  __shared__ u16 Bs[BM * BK];

  const int tid = threadIdx.x;
  const int wave = tid >> 6, lane = tid & 63;
  const int mr = lane & 15, quad = lane >> 4, mr7 = lane & 7;
  const int hwlin = blockIdx.y * 8 + blockIdx.x;        // 512 blocks
  const int swz = (hwlin & 7) * 64 + (hwlin >> 3);      // bijective
  const int m0 = (swz >> 3) * BM, n0 = (swz & 7) * BM;
  const int wm = (wave >> 1) * 64, wn = (wave & 1) * 64;
  const int ldr = lane >> 3;
  const int ldc_sw = ((lane & 7) ^ (ldr & 7)) * 8;

  const f32x4 zero = {0.f, 0.f, 0.f, 0.f};
  f32x4 acc[4][4];
  #pragma unroll
  for (int i = 0; i < 4; i++)
    #pragma unroll
    for (int j = 0; j < 4; j++) acc[i][j] = zero;

  for (int k0 = 0; k0 < K; k0 += BK) {
    __syncthreads();
    #pragma unroll
    for (int i = 0; i < 4; i++) {
      int row = wave * 32 + i * 8;
      g2l16(X + (size_t)(m0 + row + ldr) * K + k0 + ldc_sw, As + row * BK);
      g2l16(W + (size_t)(n0 + row + ldr) * K + k0 + ldc_sw, Bs + row * BK);
    }
    __syncthreads();

    #pragma unroll
    for (int c = 0; c < 2; c++) {
      bf16x8 a[4];
      #pragma unroll
      for (int i = 0; i < 4; i++)
        a[i] = *(const bf16x8*)(As + (wm + i * 16 + mr) * BK +
                                (((c * 4 + quad) ^ mr7) * 8));
      #pragma unroll
      for (int j = 0; j < 4; j++) {
        bf16x8 b = *(const bf16x8*)(Bs + (wn + j * 16 + mr) * BK +
                                    (((c * 4 + quad) ^ mr7) * 8));
        #pragma unroll
        for (int i = 0; i < 4; i++)
          acc[i][j] = __builtin_amdgcn_mfma_f32_16x16x32_bf16(
              a[i], b, acc[i][j], 0, 0, 0);
      }
    }
  }

  #pragma unroll
  for (int i = 0; i < 4; i++)
    #pragma unroll
    for (int j = 0; j < 4; j++)
      #pragma unroll
      for (int r = 0; r < 4; r++) {
        int m = m0 + wm + i * 16 + quad * 4 + r;
        int n = n0 + wn + j * 16 + mr;
        Y[(size_t)m * N + n] = acc[i][j][r];
      }
}

// ---------------------------------------------------------------------------
// Flash attention (round-11 form, best measured: 92.4 us / ~744 TF).
// REGISTER-RESIDENT P via swapped QK^T + V-permutation; 512-thread blocks
// (8 waves x 32 q-rows); streamed K/V fragments (VGPR 60, no spill);
// MFMA row-sums vs ones-vector; XCD swizzle (K/V L2-resident, FETCH 24.6MB);
// single setprio pair around the QK MFMA cluster.
// Issue-bound: 4 vs 8 waves/SIMD both ~94 us (r6/r10); in-wave pipeline
// spills (r9). Unchanged this round.
// LDS: Ks 2x8K + Vs 2x8K = 32 KB.
// ---------------------------------------------------------------------------
__global__ __launch_bounds__(512, 4)
void attn(const u16* __restrict__ Q, const u16* __restrict__ K,
          const u16* __restrict__ VT, u16* __restrict__ O) {
  __shared__ u16 Ks[2][64 * 64];     // [buf][key row][d], XOR-swizzled cols
  __shared__ u16 Vs[2][64 * 64];     // [buf][d][key], XOR-swizzled cols

  const int tid = threadIdx.x;
  const int wave = tid >> 6, lane = tid & 63;
  const int mr = lane & 15, quad = lane >> 4, mr7 = lane & 7;
  // XCD swizzle: XCD c gets heads [c*8, c*8+8) -> K/V L2-resident.
  const int hwlin = blockIdx.y * 8 + blockIdx.x;      // 512 blocks
  const int swz = (hwlin & 7) * 64 + (hwlin >> 3);    // bijective
  const int bh = swz >> 3;
  const int q0 = (swz & 7) * 256;
  const int b = bh >> 4, h = bh & 15;
  const size_t headK = (size_t)b * Sc * Dc + (size_t)h * DKc;
  const size_t headV = (size_t)bh * DKc * Sc;
  const int ldr = lane >> 3;
  const int ldc_sw = ((lane & 7) ^ (ldr & 7)) * 8;

  // per-wave staging rows: 8 waves x 8 rows = 64 rows per buffer
  const int row0 = wave * 8;
  const int pr = row0 + ldr;

  // Q fragments: 2 subtiles x 2 k-chunks (0.125*log2e folded into Q GEMM).
  bf16x8 qa[2][2];
  #pragma unroll
  for (int sub = 0; sub < 2; sub++)
    #pragma unroll
    for (int c = 0; c < 2; c++)
      qa[sub][c] = *(const bf16x8*)(Q + headK +
          (size_t)(q0 + wave * 32 + sub * 16 + mr) * Dc + c * 32 + quad * 8);

  const f32x4 zero = {0.f, 0.f, 0.f, 0.f};
  const short one_bf = (short)0x3F80;   // bf16 1.0
  const bf16x8 ones = {one_bf, one_bf, one_bf, one_bf,
                       one_bf, one_bf, one_bf, one_bf};
  f32x4 o[2][4];
  f32x4 lacc[2];
  #pragma unroll
  for (int sub = 0; sub < 2; sub++) {
    lacc[sub] = zero;
    #pragma unroll
    for (int i = 0; i < 4; i++) o[sub][i] = zero;
  }

  // stage tile 0 into buf 0 (K rows natural; V already column-permuted)
  g2l16(K + headK + (size_t)pr * Dc + ldc_sw, Ks[0] + row0 * 64);
  g2l16(VT + headV + (size_t)pr * Sc + ldc_sw, Vs[0] + row0 * 64);
  __syncthreads();

  union W8 { unsigned u[4]; bf16x8 v; };

  for (int kt = 0; kt < Sc / 64; kt++) {
    const int cur = kt & 1;
    if (kt + 1 < Sc / 64) {
      const int nk0 = (kt + 1) * 64;
      const int nxt = cur ^ 1;
      g2l16(K + headK + (size_t)(nk0 + pr) * Dc + ldc_sw, Ks[nxt] + row0 * 64);
      g2l16(VT + headV + (size_t)pr * Sc + nk0 + ldc_sw, Vs[nxt] + row0 * 64);
    }

    // swapped QK^T: stream K fragments (one kc at a time, feeds both subs)
    f32x4 s0[4], s1[4];
    __builtin_amdgcn_s_setprio(1);
    #pragma unroll
    for (int kc = 0; kc < 4; kc++) {
      bf16x8 k0 = *(const bf16x8*)(Ks[cur] + (kc * 16 + mr) * 64 +
                                   ((quad ^ mr7) * 8));
      bf16x8 k1 = *(const bf16x8*)(Ks[cur] + (kc * 16 + mr) * 64 +
                                   (((4 + quad) ^ mr7) * 8));
      s0[kc] = __builtin_amdgcn_mfma_f32_16x16x32_bf16(k0, qa[0][0], zero, 0, 0, 0);
      s1[kc] = __builtin_amdgcn_mfma_f32_16x16x32_bf16(k0, qa[1][0], zero, 0, 0, 0);
      s0[kc] = __builtin_amdgcn_mfma_f32_16x16x32_bf16(k1, qa[0][1], s0[kc], 0, 0, 0);
      s1[kc] = __builtin_amdgcn_mfma_f32_16x16x32_bf16(k1, qa[1][1], s1[kc], 0, 0, 0);
    }
    __builtin_amdgcn_s_setprio(0);

    // softmax; P packed straight into PV A-fragments (lane-local, q = mr)
    W8 paw[2][2];
    {
      float e[16];
      #pragma unroll
      for (int kc = 0; kc < 4; kc++)
        #pragma unroll
        for (int r = 0; r < 4; r++)
          e[kc * 4 + r] = fast_exp2(s0[kc][r]);
      paw[0][0].u[0] = f2b_pk(e[0], e[1]);
      paw[0][0].u[1] = f2b_pk(e[2], e[3]);
      paw[0][0].u[2] = f2b_pk(e[4], e[5]);
      paw[0][0].u[3] = f2b_pk(e[6], e[7]);
      paw[0][1].u[0] = f2b_pk(e[8], e[9]);
      paw[0][1].u[1] = f2b_pk(e[10], e[11]);
      paw[0][1].u[2] = f2b_pk(e[12], e[13]);
      paw[0][1].u[3] = f2b_pk(e[14], e[15]);
    }
    {
      float e[16];
      #pragma unroll
      for (int kc = 0; kc < 4; kc++)
        #pragma unroll
        for (int r = 0; r < 4; r++)
          e[kc * 4 + r] = fast_exp2(s1[kc][r]);
      paw[1][0].u[0] = f2b_pk(e[0], e[1]);
      paw[1][0].u[1] = f2b_pk(e[2], e[3]);
      paw[1][0].u[2] = f2b_pk(e[4], e[5]);
      paw[1][0].u[3] = f2b_pk(e[6], e[7]);
      paw[1][1].u[0] = f2b_pk(e[8], e[9]);
      paw[1][1].u[1] = f2b_pk(e[10], e[11]);
      paw[1][1].u[2] = f2b_pk(e[12], e[13]);
      paw[1][1].u[3] = f2b_pk(e[14], e[15]);
    }

    // row sums via MFMA against ones (D-layout identical to o)
    __builtin_amdgcn_s_setprio(1);
    lacc[0] = __builtin_amdgcn_mfma_f32_16x16x32_bf16(
        paw[0][0].v, ones, lacc[0], 0, 0, 0);
    lacc[0] = __builtin_amdgcn_mfma_f32_16x16x32_bf16(
        paw[0][1].v, ones, lacc[0], 0, 0, 0);
    lacc[1] = __builtin_amdgcn_mfma_f32_16x16x32_bf16(
        paw[1][0].v, ones, lacc[1], 0, 0, 0);
    lacc[1] = __builtin_amdgcn_mfma_f32_16x16x32_bf16(
        paw[1][1].v, ones, lacc[1], 0, 0, 0);
    __builtin_amdgcn_s_setprio(0);

    // PV: stream V fragments (one ni at a time, feeds both subs)
    #pragma unroll
    for (int ni = 0; ni < 4; ni++) {
      bf16x8 v0 = *(const bf16x8*)(Vs[cur] + (ni * 16 + mr) * 64 +
                                   ((quad ^ mr7) * 8));
      bf16x8 v1 = *(const bf16x8*)(Vs[cur] + (ni * 16 + mr) * 64 +
                                   (((4 + quad) ^ mr7) * 8));
      __builtin_amdgcn_s_setprio(1);
      o[0][ni] = __builtin_amdgcn_mfma_f32_16x16x32_bf16(
          paw[0][0].v, v0, o[0][ni], 0, 0, 0);
      o[1][ni] = __builtin_amdgcn_mfma_f32_16x16x32_bf16(
          paw[1][0].v, v0, o[1][ni], 0, 0, 0);
      o[0][ni] = __builtin_amdgcn_mfma_f32_16x16x32_bf16(
          paw[0][1].v, v1, o[0][ni], 0, 0, 0);
      o[1][ni] = __builtin_amdgcn_mfma_f32_16x16x32_bf16(
          paw[1][1].v, v1, o[1][ni], 0, 0, 0);
      __builtin_amdgcn_s_setprio(0);
    }

    __syncthreads();   // drains prefetch (covered by ~full tile of compute)
  }

  // epilogue: lacc[sub][r] is the row sum for q = quad*4+r (replicated over
  // the mr lanes) -- same layout as o. No shuffles.
  #pragma unroll
  for (int sub = 0; sub < 2; sub++) {
    #pragma unroll
    for (int r = 0; r < 4; r++) {
      float inv = 1.0f / lacc[sub][r];
      int qq = q0 + wave * 32 + sub * 16 + quad * 4 + r;
      #pragma unroll
      for (int ni = 0; ni < 4; ni++)
        O[headK + (size_t)qq * Dc + ni * 16 + mr] = f2b(o[sub][ni][r] * inv);
    }
  }
}

// ---------------------------------------------------------------------------
extern "C" void kernel_launch(void* const* d_in, const int* in_sizes, int n_in,
                              void* d_out, int out_size, void* d_ws, size_t ws_size,
                              hipStream_t stream) {
  const float* emb = (const float*)d_in[0];
  const float* Wq  = (const float*)d_in[1];
  const float* Wk  = (const float*)d_in[2];
  const float* Wv  = (const float*)d_in[3];
  const float* Wo  = (const float*)d_in[4];
  float* out = (float*)d_out;

  const int M = Bc * Sc;                   // 8192

  u16* Eb  = (u16*)d_ws;
  u16* Wqb = Eb  + EDc;
  u16* Wkb = Wqb + WDc;
  u16* Wvb = Wkb + WDc;
  u16* Wob = Wvb + WDc;
  u16* Qb  = Wob + WDc;
  u16* Kb  = Qb  + EDc;
  u16* VTb = Kb  + EDc;
  u16* Cb  = Qb;  // ctx overwrites Q (per-block same-slice read-then-write)

  dim3 blk(256);
  cvt_all<<<dim3(4096 + 4 * 512), blk, 0, stream>>>(emb, Wq, Wk, Wv, Wo, Eb);

  gemm_qkv<<<dim3(24, M / 128), blk, 0, stream>>>(Eb, Wqb, Wkb, Wvb,
                                                  Qb, Kb, VTb);

  attn<<<dim3(Sc / 256, Bc * Hc), dim3(512), 0, stream>>>(Qb, Kb, VTb, Cb);

  gemm_out<<<dim3(Dc / 128, M / 128), blk, 0, stream>>>(Cb, Wob, out,
                                                        M, Dc, Dc);
}

// Round 13
// 258.837 us; speedup vs baseline: 1.0020x; 1.0020x over previous
//
#include <hip/hip_runtime.h>
#include <hip/hip_bf16.h>

typedef unsigned short u16;
typedef __attribute__((ext_vector_type(8))) short bf16x8;
typedef __attribute__((ext_vector_type(4))) float f32x4;

#define AS1 __attribute__((address_space(1)))
#define AS3 __attribute__((address_space(3)))

constexpr int Bc = 4, Sc = 2048, Dc = 1024, Hc = 16, DKc = 64;
constexpr size_t EDc = (size_t)Bc * Sc * Dc;   // 8388608
constexpr size_t WDc = (size_t)Dc * Dc;        // 1048576

__device__ __forceinline__ void g2l16(const void* g, void* l) {
  __builtin_amdgcn_global_load_lds((const AS1 unsigned int*)g,
                                   (AS3 unsigned int*)l, 16, 0, 0);
}

__device__ __forceinline__ u16 f2b(float f) {
  union { float f; unsigned u; } x; x.f = f;
  unsigned r = x.u + 0x7fffu + ((x.u >> 16) & 1u);
  return (u16)(r >> 16);
}

// packed f32x2 -> bf16x2 (low = a). gfx950 has v_cvt_pk_bf16_f32.
#if __has_builtin(__builtin_amdgcn_cvt_pk_bf16_f32)
typedef __attribute__((ext_vector_type(2))) __bf16 hbf2;
__device__ __forceinline__ unsigned f2b_pk(float a, float b) {
  union { hbf2 v; unsigned u; } x;
  x.v = __builtin_amdgcn_cvt_pk_bf16_f32(a, b);
  return x.u;
}
#else
__device__ __forceinline__ unsigned f2b_pk(float a, float b) {
  return (unsigned)f2b(a) | ((unsigned)f2b(b) << 16);
}
#endif

__device__ __forceinline__ float fast_exp2(float x) {
#if __has_builtin(__builtin_amdgcn_exp2f)
  return __builtin_amdgcn_exp2f(x);
#else
  return exp2f(x);
#endif
}

// ---------------------------------------------------------------------------
// Fused fp32->bf16 for all 5 inputs (dest regions contiguous in ws).
// ---------------------------------------------------------------------------
__global__ __launch_bounds__(256)
void cvt_all(const float* __restrict__ e, const float* __restrict__ wq,
             const float* __restrict__ wk, const float* __restrict__ wv,
             const float* __restrict__ wo, u16* __restrict__ dst) {
  int bx = blockIdx.x;
  const float* src;
  size_t doff;
  int chunk;
  if (bx < 4096) {
    src = e; doff = 0; chunk = bx;
  } else {
    int t = bx - 4096;
    int w = t >> 9;
    chunk = t & 511;
    src = (w == 0) ? wq : (w == 1) ? wk : (w == 2) ? wv : wo;
    doff = EDc + (size_t)w * WDc;
  }
  size_t i = ((size_t)chunk * 256 + threadIdx.x) * 8;
  float4 a = *(const float4*)(src + i);
  float4 b = *(const float4*)(src + i + 4);
  bf16x8 o;
  o[0] = (short)f2b(a.x); o[1] = (short)f2b(a.y);
  o[2] = (short)f2b(a.z); o[3] = (short)f2b(a.w);
  o[4] = (short)f2b(b.x); o[5] = (short)f2b(b.y);
  o[6] = (short)f2b(b.z); o[7] = (short)f2b(b.w);
  *(bf16x8*)(dst + doff + i) = o;
}

// ---------------------------------------------------------------------------
// Fused QKV GEMM (round-11 form -- session best; GEMM micro-structure proven
// insensitive over rounds 6/7/8/12 variants, occupancy-forcing refuted in
// rounds 5/12). sect 0 = Q (0.125*log2e folded), 1 = K, 2 = V
// (operand-swapped -> contiguous VT stores, within-64-key permutation
// pos(k): [h|b|qq|r] -> [h|qq|b|r] matching attn's register-resident P).
// XCD swizzle: each XCD owns 8 consecutive m-panels.
// ---------------------------------------------------------------------------
__global__ __launch_bounds__(256, 2)
void gemm_qkv(const u16* __restrict__ X, const u16* __restrict__ Wq,
              const u16* __restrict__ Wk, const u16* __restrict__ Wv,
              u16* __restrict__ Qo, u16* __restrict__ Ko,
              u16* __restrict__ VTo) {
  constexpr int BM = 128, BK = 64, K = Dc, N = Dc;
  __shared__ u16 As[BM * BK];
  __shared__ u16 Bs[BM * BK];

  const int tid = threadIdx.x;
  const int wave = tid >> 6, lane = tid & 63;
  const int mr = lane & 15, quad = lane >> 4, mr7 = lane & 7;
  const int hwlin = blockIdx.y * 24 + blockIdx.x;        // 1536 blocks
  const int swz = (hwlin & 7) * 192 + (hwlin >> 3);      // bijective
  const int lx = swz % 24, ly = swz / 24;
  const int sect = lx >> 3;
  const int n0 = (lx & 7) * 128;
  const int m0 = ly * BM;
  const u16* W = (sect == 0) ? Wq : (sect == 1) ? Wk : Wv;
  const int wm = (wave >> 1) * 64, wn = (wave & 1) * 64;
  const int ldr = lane >> 3;
  const int ldc_sw = ((lane & 7) ^ (ldr & 7)) * 8;
  const bool vsec = (sect == 2);

  const f32x4 zero = {0.f, 0.f, 0.f, 0.f};
  f32x4 acc[4][4];
  #pragma unroll
  for (int i = 0; i < 4; i++)
    #pragma unroll
    for (int j = 0; j < 4; j++) acc[i][j] = zero;

  for (int k0 = 0; k0 < K; k0 += BK) {
    __syncthreads();
    #pragma unroll
    for (int i = 0; i < 4; i++) {
      int row = wave * 32 + i * 8;
      g2l16(X + (size_t)(m0 + row + ldr) * K + k0 + ldc_sw, As + row * BK);
      g2l16(W + (size_t)(n0 + row + ldr) * K + k0 + ldc_sw, Bs + row * BK);
    }
    __syncthreads();

    #pragma unroll
    for (int c = 0; c < 2; c++) {
      bf16x8 a[4], b[4];
      #pragma unroll
      for (int i = 0; i < 4; i++)
        a[i] = *(const bf16x8*)(As + (wm + i * 16 + mr) * BK +
                                (((c * 4 + quad) ^ mr7) * 8));
      #pragma unroll
      for (int j = 0; j < 4; j++)
        b[j] = *(const bf16x8*)(Bs + (wn + j * 16 + mr) * BK +
                                (((c * 4 + quad) ^ mr7) * 8));
      if (vsec) {
        #pragma unroll
        for (int i = 0; i < 4; i++)
          #pragma unroll
          for (int j = 0; j < 4; j++)
            acc[i][j] = __builtin_amdgcn_mfma_f32_16x16x32_bf16(
                b[j], a[i], acc[i][j], 0, 0, 0);   // D = Y^T tile
      } else {
        #pragma unroll
        for (int i = 0; i < 4; i++)
          #pragma unroll
          for (int j = 0; j < 4; j++)
            acc[i][j] = __builtin_amdgcn_mfma_f32_16x16x32_bf16(
                a[i], b[j], acc[i][j], 0, 0, 0);
      }
    }
  }

  if (vsec) {
    #pragma unroll
    for (int i = 0; i < 4; i++) {
      int s_glob = m0 + wm + i * 16 + mr;
      int bb = s_glob >> 11, s = s_glob & 2047;
      int sp = (s & ~63) | (s & 32) | ((s & 12) << 1) | ((s & 16) >> 2) |
               (s & 3);
      #pragma unroll
      for (int j = 0; j < 4; j++) {
        int nbase = n0 + wn + j * 16 + quad * 4;
        #pragma unroll
        for (int r = 0; r < 4; r++) {
          int n = nbase + r;
          int h = n >> 6, d = n & 63;
          VTo[((size_t)((bb * Hc + h) * DKc + d)) * Sc + sp] = f2b(acc[i][j][r]);
        }
      }
    }
  } else {
    const float scale = (sect == 0) ? 0.18033688f : 1.0f;
    u16* Y = (sect == 0) ? Qo : Ko;
    #pragma unroll
    for (int i = 0; i < 4; i++)
      #pragma unroll
      for (int j = 0; j < 4; j++)
        #pragma unroll
        for (int r = 0; r < 4; r++) {
          int m = m0 + wm + i * 16 + quad * 4 + r;
          int n = n0 + wn + j * 16 + mr;
          Y[(size_t)m * N + n] = f2b(acc[i][j][r] * scale);
        }
  }
}

// ---------------------------------------------------------------------------
// Output GEMM: out = ctx @ Wo.T, fp32 output (round-11 form). XCD swizzle.
// ---------------------------------------------------------------------------
__global__ __launch_bounds__(256, 2)
void gemm_out(const u16* __restrict__ X, const u16* __restrict__ W,
              float* __restrict__ Y, int M, int N, int K) {
  constexpr int BM = 128, BK = 64;
  __shared__ u16 As[BM * BK];
  __shared__ u16 Bs[BM * BK];

  const int tid = threadIdx.x;
  const int wave = tid >> 6, lane = tid & 63;
  const int mr = lane & 15, quad = lane >> 4, mr7 = lane & 7;
  const int hwlin = blockIdx.y * 8 + blockIdx.x;        // 512 blocks
  const int swz = (hwlin & 7) * 64 + (hwlin >> 3);      // bijective
  const int m0 = (swz >> 3) * BM, n0 = (swz & 7) * BM;
  const int wm = (wave >> 1) * 64, wn = (wave & 1) * 64;
  const int ldr = lane >> 3;
  const int ldc_sw = ((lane & 7) ^ (ldr & 7)) * 8;

  const f32x4 zero = {0.f, 0.f, 0.f, 0.f};
  f32x4 acc[4][4];
  #pragma unroll
  for (int i = 0; i < 4; i++)
    #pragma unroll
    for (int j = 0; j < 4; j++) acc[i][j] = zero;

  for (int k0 = 0; k0 < K; k0 += BK) {
    __syncthreads();
    #pragma unroll
    for (int i = 0; i < 4; i++) {
      int row = wave * 32 + i * 8;
      g2l16(X + (size_t)(m0 + row + ldr) * K + k0 + ldc_sw, As + row * BK);
      g2l16(W + (size_t)(n0 + row + ldr) * K + k0 + ldc_sw, Bs + row * BK);
    }
    __syncthreads();

    #pragma unroll
    for (int c = 0; c < 2; c++) {
      bf16x8 a[4], b[4];
      #pragma unroll
      for (int i = 0; i < 4; i++)
        a[i] = *(const bf16x8*)(As + (wm + i * 16 + mr) * BK +
                                (((c * 4 + quad) ^ mr7) * 8));
      #pragma unroll
      for (int j = 0; j < 4; j++)
        b[j] = *(const bf16x8*)(Bs + (wn + j * 16 + mr) * BK +
                                (((c * 4 + quad) ^ mr7) * 8));
      #pragma unroll
      for (int i = 0; i < 4; i++)
        #pragma unroll
        for (int j = 0; j < 4; j++)
          acc[i][j] = __builtin_amdgcn_mfma_f32_16x16x32_bf16(
              a[i], b[j], acc[i][j], 0, 0, 0);
    }
  }

  #pragma unroll
  for (int i = 0; i < 4; i++)
    #pragma unroll
    for (int j = 0; j < 4; j++)
      #pragma unroll
      for (int r = 0; r < 4; r++) {
        int m = m0 + wm + i * 16 + quad * 4 + r;
        int n = n0 + wn + j * 16 + mr;
        Y[(size_t)m * N + n] = acc[i][j][r];
      }
}

// ---------------------------------------------------------------------------
// Flash attention (round-11 form, session best: 92.2 us / ~744 TF).
// REGISTER-RESIDENT P via swapped QK^T + V-permutation; 512-thread blocks
// (8 waves x 32 q-rows); streamed K/V fragments (VGPR 60, no spill);
// MFMA row-sums vs ones-vector (shuffle-free epilogue); XCD swizzle
// (per-head K/V L2-resident: FETCH 139->24.6 MB); single setprio pair
// around the QK MFMA cluster.
// Characterized issue-bound: 4 vs 8 waves/SIMD both ~94 us (r6/r10);
// in-wave pipelining spills at the 128-VGPR cap (r9). Remaining lever is
// a 32x32-MFMA rewrite (halves MFMA issue slots) -- needs HW layout
// verification not available headlessly.
// LDS: Ks 2x8K + Vs 2x8K = 32 KB.
// ---------------------------------------------------------------------------
__global__ __launch_bounds__(512, 4)
void attn(const u16* __restrict__ Q, const u16* __restrict__ K,
          const u16* __restrict__ VT, u16* __restrict__ O) {
  __shared__ u16 Ks[2][64 * 64];     // [buf][key row][d], XOR-swizzled cols
  __shared__ u16 Vs[2][64 * 64];     // [buf][d][key], XOR-swizzled cols

  const int tid = threadIdx.x;
  const int wave = tid >> 6, lane = tid & 63;
  const int mr = lane & 15, quad = lane >> 4, mr7 = lane & 7;
  // XCD swizzle: XCD c gets heads [c*8, c*8+8) -> K/V L2-resident.
  const int hwlin = blockIdx.y * 8 + blockIdx.x;      // 512 blocks
  const int swz = (hwlin & 7) * 64 + (hwlin >> 3);    // bijective
  const int bh = swz >> 3;
  const int q0 = (swz & 7) * 256;
  const int b = bh >> 4, h = bh & 15;
  const size_t headK = (size_t)b * Sc * Dc + (size_t)h * DKc;
  const size_t headV = (size_t)bh * DKc * Sc;
  const int ldr = lane >> 3;
  const int ldc_sw = ((lane & 7) ^ (ldr & 7)) * 8;

  // per-wave staging rows: 8 waves x 8 rows = 64 rows per buffer
  const int row0 = wave * 8;
  const int pr = row0 + ldr;

  // Q fragments: 2 subtiles x 2 k-chunks (0.125*log2e folded into Q GEMM).
  bf16x8 qa[2][2];
  #pragma unroll
  for (int sub = 0; sub < 2; sub++)
    #pragma unroll
    for (int c = 0; c < 2; c++)
      qa[sub][c] = *(const bf16x8*)(Q + headK +
          (size_t)(q0 + wave * 32 + sub * 16 + mr) * Dc + c * 32 + quad * 8);

  const f32x4 zero = {0.f, 0.f, 0.f, 0.f};
  const short one_bf = (short)0x3F80;   // bf16 1.0
  const bf16x8 ones = {one_bf, one_bf, one_bf, one_bf,
                       one_bf, one_bf, one_bf, one_bf};
  f32x4 o[2][4];
  f32x4 lacc[2];
  #pragma unroll
  for (int sub = 0; sub < 2; sub++) {
    lacc[sub] = zero;
    #pragma unroll
    for (int i = 0; i < 4; i++) o[sub][i] = zero;
  }

  // stage tile 0 into buf 0 (K rows natural; V already column-permuted)
  g2l16(K + headK + (size_t)pr * Dc + ldc_sw, Ks[0] + row0 * 64);
  g2l16(VT + headV + (size_t)pr * Sc + ldc_sw, Vs[0] + row0 * 64);
  __syncthreads();

  union W8 { unsigned u[4]; bf16x8 v; };

  for (int kt = 0; kt < Sc / 64; kt++) {
    const int cur = kt & 1;
    if (kt + 1 < Sc / 64) {
      const int nk0 = (kt + 1) * 64;
      const int nxt = cur ^ 1;
      g2l16(K + headK + (size_t)(nk0 + pr) * Dc + ldc_sw, Ks[nxt] + row0 * 64);
      g2l16(VT + headV + (size_t)pr * Sc + nk0 + ldc_sw, Vs[nxt] + row0 * 64);
    }

    // swapped QK^T: stream K fragments (one kc at a time, feeds both subs)
    f32x4 s0[4], s1[4];
    __builtin_amdgcn_s_setprio(1);
    #pragma unroll
    for (int kc = 0; kc < 4; kc++) {
      bf16x8 k0 = *(const bf16x8*)(Ks[cur] + (kc * 16 + mr) * 64 +
                                   ((quad ^ mr7) * 8));
      bf16x8 k1 = *(const bf16x8*)(Ks[cur] + (kc * 16 + mr) * 64 +
                                   (((4 + quad) ^ mr7) * 8));
      s0[kc] = __builtin_amdgcn_mfma_f32_16x16x32_bf16(k0, qa[0][0], zero, 0, 0, 0);
      s1[kc] = __builtin_amdgcn_mfma_f32_16x16x32_bf16(k0, qa[1][0], zero, 0, 0, 0);
      s0[kc] = __builtin_amdgcn_mfma_f32_16x16x32_bf16(k1, qa[0][1], s0[kc], 0, 0, 0);
      s1[kc] = __builtin_amdgcn_mfma_f32_16x16x32_bf16(k1, qa[1][1], s1[kc], 0, 0, 0);
    }
    __builtin_amdgcn_s_setprio(0);

    // softmax; P packed straight into PV A-fragments (lane-local, q = mr)
    W8 paw[2][2];
    {
      float e[16];
      #pragma unroll
      for (int kc = 0; kc < 4; kc++)
        #pragma unroll
        for (int r = 0; r < 4; r++)
          e[kc * 4 + r] = fast_exp2(s0[kc][r]);
      paw[0][0].u[0] = f2b_pk(e[0], e[1]);
      paw[0][0].u[1] = f2b_pk(e[2], e[3]);
      paw[0][0].u[2] = f2b_pk(e[4], e[5]);
      paw[0][0].u[3] = f2b_pk(e[6], e[7]);
      paw[0][1].u[0] = f2b_pk(e[8], e[9]);
      paw[0][1].u[1] = f2b_pk(e[10], e[11]);
      paw[0][1].u[2] = f2b_pk(e[12], e[13]);
      paw[0][1].u[3] = f2b_pk(e[14], e[15]);
    }
    {
      float e[16];
      #pragma unroll
      for (int kc = 0; kc < 4; kc++)
        #pragma unroll
        for (int r = 0; r < 4; r++)
          e[kc * 4 + r] = fast_exp2(s1[kc][r]);
      paw[1][0].u[0] = f2b_pk(e[0], e[1]);
      paw[1][0].u[1] = f2b_pk(e[2], e[3]);
      paw[1][0].u[2] = f2b_pk(e[4], e[5]);
      paw[1][0].u[3] = f2b_pk(e[6], e[7]);
      paw[1][1].u[0] = f2b_pk(e[8], e[9]);
      paw[1][1].u[1] = f2b_pk(e[10], e[11]);
      paw[1][1].u[2] = f2b_pk(e[12], e[13]);
      paw[1][1].u[3] = f2b_pk(e[14], e[15]);
    }

    // row sums via MFMA against ones (D-layout identical to o)
    __builtin_amdgcn_s_setprio(1);
    lacc[0] = __builtin_amdgcn_mfma_f32_16x16x32_bf16(
        paw[0][0].v, ones, lacc[0], 0, 0, 0);
    lacc[0] = __builtin_amdgcn_mfma_f32_16x16x32_bf16(
        paw[0][1].v, ones, lacc[0], 0, 0, 0);
    lacc[1] = __builtin_amdgcn_mfma_f32_16x16x32_bf16(
        paw[1][0].v, ones, lacc[1], 0, 0, 0);
    lacc[1] = __builtin_amdgcn_mfma_f32_16x16x32_bf16(
        paw[1][1].v, ones, lacc[1], 0, 0, 0);
    __builtin_amdgcn_s_setprio(0);

    // PV: stream V fragments (one ni at a time, feeds both subs)
    #pragma unroll
    for (int ni = 0; ni < 4; ni++) {
      bf16x8 v0 = *(const bf16x8*)(Vs[cur] + (ni * 16 + mr) * 64 +
                                   ((quad ^ mr7) * 8));
      bf16x8 v1 = *(const bf16x8*)(Vs[cur] + (ni * 16 + mr) * 64 +
                                   (((4 + quad) ^ mr7) * 8));
      __builtin_amdgcn_s_setprio(1);
      o[0][ni] = __builtin_amdgcn_mfma_f32_16x16x32_bf16(
          paw[0][0].v, v0, o[0][ni], 0, 0, 0);
      o[1][ni] = __builtin_amdgcn_mfma_f32_16x16x32_bf16(
          paw[1][0].v, v0, o[1][ni], 0, 0, 0);
      o[0][ni] = __builtin_amdgcn_mfma_f32_16x16x32_bf16(
          paw[0][1].v, v1, o[0][ni], 0, 0, 0);
      o[1][ni] = __builtin_amdgcn_mfma_f32_16x16x32_bf16(
          paw[1][1].v, v1, o[1][ni], 0, 0, 0);
      __builtin_amdgcn_s_setprio(0);
    }

    __syncthreads();   // drains prefetch (covered by ~full tile of compute)
  }

  // epilogue: lacc[sub][r] is the row sum for q = quad*4+r (replicated over
  // the mr lanes) -- same layout as o. No shuffles.
  #pragma unroll
  for (int sub = 0; sub < 2; sub++) {
    #pragma unroll
    for (int r = 0; r < 4; r++) {
      float inv = 1.0f / lacc[sub][r];
      int qq = q0 + wave * 32 + sub * 16 + quad * 4 + r;
      #pragma unroll
      for (int ni = 0; ni < 4; ni++)
        O[headK + (size_t)qq * Dc + ni * 16 + mr] = f2b(o[sub][ni][r] * inv);
    }
  }
}

// ---------------------------------------------------------------------------
extern "C" void kernel_launch(void* const* d_in, const int* in_sizes, int n_in,
                              void* d_out, int out_size, void* d_ws, size_t ws_size,
                              hipStream_t stream) {
  const float* emb = (const float*)d_in[0];
  const float* Wq  = (const float*)d_in[1];
  const float* Wk  = (const float*)d_in[2];
  const float* Wv  = (const float*)d_in[3];
  const float* Wo  = (const float*)d_in[4];
  float* out = (float*)d_out;

  const int M = Bc * Sc;                   // 8192

  u16* Eb  = (u16*)d_ws;
  u16* Wqb = Eb  + EDc;
  u16* Wkb = Wqb + WDc;
  u16* Wvb = Wkb + WDc;
  u16* Wob = Wvb + WDc;
  u16* Qb  = Wob + WDc;
  u16* Kb  = Qb  + EDc;
  u16* VTb = Kb  + EDc;
  u16* Cb  = Qb;  // ctx overwrites Q (per-block same-slice read-then-write)

  dim3 blk(256);
  cvt_all<<<dim3(4096 + 4 * 512), blk, 0, stream>>>(emb, Wq, Wk, Wv, Wo, Eb);

  gemm_qkv<<<dim3(24, M / 128), blk, 0, stream>>>(Eb, Wqb, Wkb, Wvb,
                                                  Qb, Kb, VTb);

  attn<<<dim3(Sc / 256, Bc * Hc), dim3(512), 0, stream>>>(Qb, Kb, VTb, Cb);

  gemm_out<<<dim3(Dc / 128, M / 128), blk, 0, stream>>>(Cb, Wob, out,
                                                        M, Dc, Dc);
}

// Round 14
// 248.384 us; speedup vs baseline: 1.0442x; 1.0421x over previous
//
#include <hip/hip_runtime.h>
#include <hip/hip_bf16.h>

typedef unsigned short u16;
typedef __attribute__((ext_vector_type(8))) short bf16x8;
typedef __attribute__((ext_vector_type(4))) float f32x4;

#define AS1 __attribute__((address_space(1)))
#define AS3 __attribute__((address_space(3)))

constexpr int Bc = 4, Sc = 2048, Dc = 1024, Hc = 16, DKc = 64;
constexpr size_t EDc = (size_t)Bc * Sc * Dc;   // 8388608
constexpr size_t WDc = (size_t)Dc * Dc;        // 1048576

__device__ __forceinline__ void g2l16(const void* g, void* l) {
  __builtin_amdgcn_global_load_lds((const AS1 unsigned int*)g,
                                   (AS3 unsigned int*)l, 16, 0, 0);
}

// fp32 -> bf16 via native cast: hipcc emits HW v_cvt (and FUSES adjacent
// pairs into v_cvt_pk_bf16_f32 -- m240: compiler handles it; the previous
// manual RTNE bit-twiddle (~10 VALU ops/pair, since the cvt_pk builtin
// does NOT exist on gfx950 and the __has_builtin guard silently fell back)
// was the hidden VALU hog: ~320 extra cyc/wave-tile in attn.
__device__ __forceinline__ u16 f2b(float f) {
  union { __bf16 h; u16 u; } x;
  x.h = (__bf16)f;
  return x.u;
}

__device__ __forceinline__ unsigned f2b_pk(float a, float b) {
  union { __bf16 h[2]; unsigned u; } x;
  x.h[0] = (__bf16)a;
  x.h[1] = (__bf16)b;
  return x.u;
}

__device__ __forceinline__ float fast_exp2(float x) {
#if __has_builtin(__builtin_amdgcn_exp2f)
  return __builtin_amdgcn_exp2f(x);
#else
  return exp2f(x);
#endif
}

// ---------------------------------------------------------------------------
// Fused fp32->bf16 for all 5 inputs (dest regions contiguous in ws).
// ---------------------------------------------------------------------------
__global__ __launch_bounds__(256)
void cvt_all(const float* __restrict__ e, const float* __restrict__ wq,
             const float* __restrict__ wk, const float* __restrict__ wv,
             const float* __restrict__ wo, u16* __restrict__ dst) {
  int bx = blockIdx.x;
  const float* src;
  size_t doff;
  int chunk;
  if (bx < 4096) {
    src = e; doff = 0; chunk = bx;
  } else {
    int t = bx - 4096;
    int w = t >> 9;
    chunk = t & 511;
    src = (w == 0) ? wq : (w == 1) ? wk : (w == 2) ? wv : wo;
    doff = EDc + (size_t)w * WDc;
  }
  size_t i = ((size_t)chunk * 256 + threadIdx.x) * 8;
  float4 a = *(const float4*)(src + i);
  float4 b = *(const float4*)(src + i + 4);
  bf16x8 o;
  o[0] = (short)f2b(a.x); o[1] = (short)f2b(a.y);
  o[2] = (short)f2b(a.z); o[3] = (short)f2b(a.w);
  o[4] = (short)f2b(b.x); o[5] = (short)f2b(b.y);
  o[6] = (short)f2b(b.z); o[7] = (short)f2b(b.w);
  *(bf16x8*)(dst + doff + i) = o;
}

// ---------------------------------------------------------------------------
// Fused QKV GEMM (round-11 form -- session best; GEMM micro-structure proven
// insensitive over rounds 6/7/8/12 variants, occupancy-forcing refuted in
// rounds 5/12). sect 0 = Q (0.125*log2e folded), 1 = K, 2 = V
// (operand-swapped -> contiguous VT stores, within-64-key permutation
// pos(k): [h|b|qq|r] -> [h|qq|b|r] matching attn's register-resident P).
// XCD swizzle: each XCD owns 8 consecutive m-panels.
// ---------------------------------------------------------------------------
__global__ __launch_bounds__(256, 2)
void gemm_qkv(const u16* __restrict__ X, const u16* __restrict__ Wq,
              const u16* __restrict__ Wk, const u16* __restrict__ Wv,
              u16* __restrict__ Qo, u16* __restrict__ Ko,
              u16* __restrict__ VTo) {
  constexpr int BM = 128, BK = 64, K = Dc, N = Dc;
  __shared__ u16 As[BM * BK];
  __shared__ u16 Bs[BM * BK];

  const int tid = threadIdx.x;
  const int wave = tid >> 6, lane = tid & 63;
  const int mr = lane & 15, quad = lane >> 4, mr7 = lane & 7;
  const int hwlin = blockIdx.y * 24 + blockIdx.x;        // 1536 blocks
  const int swz = (hwlin & 7) * 192 + (hwlin >> 3);      // bijective
  const int lx = swz % 24, ly = swz / 24;
  const int sect = lx >> 3;
  const int n0 = (lx & 7) * 128;
  const int m0 = ly * BM;
  const u16* W = (sect == 0) ? Wq : (sect == 1) ? Wk : Wv;
  const int wm = (wave >> 1) * 64, wn = (wave & 1) * 64;
  const int ldr = lane >> 3;
  const int ldc_sw = ((lane & 7) ^ (ldr & 7)) * 8;
  const bool vsec = (sect == 2);

  const f32x4 zero = {0.f, 0.f, 0.f, 0.f};
  f32x4 acc[4][4];
  #pragma unroll
  for (int i = 0; i < 4; i++)
    #pragma unroll
    for (int j = 0; j < 4; j++) acc[i][j] = zero;

  for (int k0 = 0; k0 < K; k0 += BK) {
    __syncthreads();
    #pragma unroll
    for (int i = 0; i < 4; i++) {
      int row = wave * 32 + i * 8;
      g2l16(X + (size_t)(m0 + row + ldr) * K + k0 + ldc_sw, As + row * BK);
      g2l16(W + (size_t)(n0 + row + ldr) * K + k0 + ldc_sw, Bs + row * BK);
    }
    __syncthreads();

    #pragma unroll
    for (int c = 0; c < 2; c++) {
      bf16x8 a[4], b[4];
      #pragma unroll
      for (int i = 0; i < 4; i++)
        a[i] = *(const bf16x8*)(As + (wm + i * 16 + mr) * BK +
                                (((c * 4 + quad) ^ mr7) * 8));
      #pragma unroll
      for (int j = 0; j < 4; j++)
        b[j] = *(const bf16x8*)(Bs + (wn + j * 16 + mr) * BK +
                                (((c * 4 + quad) ^ mr7) * 8));
      if (vsec) {
        #pragma unroll
        for (int i = 0; i < 4; i++)
          #pragma unroll
          for (int j = 0; j < 4; j++)
            acc[i][j] = __builtin_amdgcn_mfma_f32_16x16x32_bf16(
                b[j], a[i], acc[i][j], 0, 0, 0);   // D = Y^T tile
      } else {
        #pragma unroll
        for (int i = 0; i < 4; i++)
          #pragma unroll
          for (int j = 0; j < 4; j++)
            acc[i][j] = __builtin_amdgcn_mfma_f32_16x16x32_bf16(
                a[i], b[j], acc[i][j], 0, 0, 0);
      }
    }
  }

  if (vsec) {
    #pragma unroll
    for (int i = 0; i < 4; i++) {
      int s_glob = m0 + wm + i * 16 + mr;
      int bb = s_glob >> 11, s = s_glob & 2047;
      int sp = (s & ~63) | (s & 32) | ((s & 12) << 1) | ((s & 16) >> 2) |
               (s & 3);
      #pragma unroll
      for (int j = 0; j < 4; j++) {
        int nbase = n0 + wn + j * 16 + quad * 4;
        #pragma unroll
        for (int r = 0; r < 4; r++) {
          int n = nbase + r;
          int h = n >> 6, d = n & 63;
          VTo[((size_t)((bb * Hc + h) * DKc + d)) * Sc + sp] = f2b(acc[i][j][r]);
        }
      }
    }
  } else {
    const float scale = (sect == 0) ? 0.18033688f : 1.0f;
    u16* Y = (sect == 0) ? Qo : Ko;
    #pragma unroll
    for (int i = 0; i < 4; i++)
      #pragma unroll
      for (int j = 0; j < 4; j++)
        #pragma unroll
        for (int r = 0; r < 4; r++) {
          int m = m0 + wm + i * 16 + quad * 4 + r;
          int n = n0 + wn + j * 16 + mr;
          Y[(size_t)m * N + n] = f2b(acc[i][j][r] * scale);
        }
  }
}

// ---------------------------------------------------------------------------
// Output GEMM: out = ctx @ Wo.T, fp32 output (round-11 form). XCD swizzle.
// ---------------------------------------------------------------------------
__global__ __launch_bounds__(256, 2)
void gemm_out(const u16* __restrict__ X, const u16* __restrict__ W,
              float* __restrict__ Y, int M, int N, int K) {
  constexpr int BM = 128, BK = 64;
  __shared__ u16 As[BM * BK];
  __shared__ u16 Bs[BM * BK];

  const int tid = threadIdx.x;
  const int wave = tid >> 6, lane = tid & 63;
  const int mr = lane & 15, quad = lane >> 4, mr7 = lane & 7;
  const int hwlin = blockIdx.y * 8 + blockIdx.x;        // 512 blocks
  const int swz = (hwlin & 7) * 64 + (hwlin >> 3);      // bijective
  const int m0 = (swz >> 3) * BM, n0 = (swz & 7) * BM;
  const int wm = (wave >> 1) * 64, wn = (wave & 1) * 64;
  const int ldr = lane >> 3;
  const int ldc_sw = ((lane & 7) ^ (ldr & 7)) * 8;

  const f32x4 zero = {0.f, 0.f, 0.f, 0.f};
  f32x4 acc[4][4];
  #pragma unroll
  for (int i = 0; i < 4; i++)
    #pragma unroll
    for (int j = 0; j < 4; j++) acc[i][j] = zero;

  for (int k0 = 0; k0 < K; k0 += BK) {
    __syncthreads();
    #pragma unroll
    for (int i = 0; i < 4; i++) {
      int row = wave * 32 + i * 8;
      g2l16(X + (size_t)(m0 + row + ldr) * K + k0 + ldc_sw, As + row * BK);
      g2l16(W + (size_t)(n0 + row + ldr) * K + k0 + ldc_sw, Bs + row * BK);
    }
    __syncthreads();

    #pragma unroll
    for (int c = 0; c < 2; c++) {
      bf16x8 a[4], b[4];
      #pragma unroll
      for (int i = 0; i < 4; i++)
        a[i] = *(const bf16x8*)(As + (wm + i * 16 + mr) * BK +
                                (((c * 4 + quad) ^ mr7) * 8));
      #pragma unroll
      for (int j = 0; j < 4; j++)
        b[j] = *(const bf16x8*)(Bs + (wn + j * 16 + mr) * BK +
                                (((c * 4 + quad) ^ mr7) * 8));
      #pragma unroll
      for (int i = 0; i < 4; i++)
        #pragma unroll
        for (int j = 0; j < 4; j++)
          acc[i][j] = __builtin_amdgcn_mfma_f32_16x16x32_bf16(
              a[i], b[j], acc[i][j], 0, 0, 0);
    }
  }

  #pragma unroll
  for (int i = 0; i < 4; i++)
    #pragma unroll
    for (int j = 0; j < 4; j++)
      #pragma unroll
      for (int r = 0; r < 4; r++) {
        int m = m0 + wm + i * 16 + quad * 4 + r;
        int n = n0 + wn + j * 16 + mr;
        Y[(size_t)m * N + n] = acc[i][j][r];
      }
}

// ---------------------------------------------------------------------------
// Flash attention (round-11 structure; round-14: native-cast bf16 packing).
// REGISTER-RESIDENT P via swapped QK^T + V-permutation; 512-thread blocks
// (8 waves x 32 q-rows); streamed K/V fragments; MFMA row-sums vs
// ones-vector; XCD swizzle (K/V L2-resident, FETCH 24.6MB); single setprio
// pair around the QK MFMA cluster.
// The f2b_pk fallback (manual RTNE bit-twiddle, ~10 VALU/pair) was ~320
// extra VALU cyc/wave-tile -- the unexplained bulk of VALUBusy=52%.
// Native casts emit HW v_cvt_pk_bf16_f32.
// LDS: Ks 2x8K + Vs 2x8K = 32 KB.
// ---------------------------------------------------------------------------
__global__ __launch_bounds__(512, 4)
void attn(const u16* __restrict__ Q, const u16* __restrict__ K,
          const u16* __restrict__ VT, u16* __restrict__ O) {
  __shared__ u16 Ks[2][64 * 64];     // [buf][key row][d], XOR-swizzled cols
  __shared__ u16 Vs[2][64 * 64];     // [buf][d][key], XOR-swizzled cols

  const int tid = threadIdx.x;
  const int wave = tid >> 6, lane = tid & 63;
  const int mr = lane & 15, quad = lane >> 4, mr7 = lane & 7;
  // XCD swizzle: XCD c gets heads [c*8, c*8+8) -> K/V L2-resident.
  const int hwlin = blockIdx.y * 8 + blockIdx.x;      // 512 blocks
  const int swz = (hwlin & 7) * 64 + (hwlin >> 3);    // bijective
  const int bh = swz >> 3;
  const int q0 = (swz & 7) * 256;
  const int b = bh >> 4, h = bh & 15;
  const size_t headK = (size_t)b * Sc * Dc + (size_t)h * DKc;
  const size_t headV = (size_t)bh * DKc * Sc;
  const int ldr = lane >> 3;
  const int ldc_sw = ((lane & 7) ^ (ldr & 7)) * 8;

  // per-wave staging rows: 8 waves x 8 rows = 64 rows per buffer
  const int row0 = wave * 8;
  const int pr = row0 + ldr;

  // Q fragments: 2 subtiles x 2 k-chunks (0.125*log2e folded into Q GEMM).
  bf16x8 qa[2][2];
  #pragma unroll
  for (int sub = 0; sub < 2; sub++)
    #pragma unroll
    for (int c = 0; c < 2; c++)
      qa[sub][c] = *(const bf16x8*)(Q + headK +
          (size_t)(q0 + wave * 32 + sub * 16 + mr) * Dc + c * 32 + quad * 8);

  const f32x4 zero = {0.f, 0.f, 0.f, 0.f};
  const short one_bf = (short)0x3F80;   // bf16 1.0
  const bf16x8 ones = {one_bf, one_bf, one_bf, one_bf,
                       one_bf, one_bf, one_bf, one_bf};
  f32x4 o[2][4];
  f32x4 lacc[2];
  #pragma unroll
  for (int sub = 0; sub < 2; sub++) {
    lacc[sub] = zero;
    #pragma unroll
    for (int i = 0; i < 4; i++) o[sub][i] = zero;
  }

  // stage tile 0 into buf 0 (K rows natural; V already column-permuted)
  g2l16(K + headK + (size_t)pr * Dc + ldc_sw, Ks[0] + row0 * 64);
  g2l16(VT + headV + (size_t)pr * Sc + ldc_sw, Vs[0] + row0 * 64);
  __syncthreads();

  union W8 { unsigned u[4]; bf16x8 v; };

  for (int kt = 0; kt < Sc / 64; kt++) {
    const int cur = kt & 1;
    if (kt + 1 < Sc / 64) {
      const int nk0 = (kt + 1) * 64;
      const int nxt = cur ^ 1;
      g2l16(K + headK + (size_t)(nk0 + pr) * Dc + ldc_sw, Ks[nxt] + row0 * 64);
      g2l16(VT + headV + (size_t)pr * Sc + nk0 + ldc_sw, Vs[nxt] + row0 * 64);
    }

    // swapped QK^T: stream K fragments (one kc at a time, feeds both subs)
    f32x4 s0[4], s1[4];
    __builtin_amdgcn_s_setprio(1);
    #pragma unroll
    for (int kc = 0; kc < 4; kc++) {
      bf16x8 k0 = *(const bf16x8*)(Ks[cur] + (kc * 16 + mr) * 64 +
                                   ((quad ^ mr7) * 8));
      bf16x8 k1 = *(const bf16x8*)(Ks[cur] + (kc * 16 + mr) * 64 +
                                   (((4 + quad) ^ mr7) * 8));
      s0[kc] = __builtin_amdgcn_mfma_f32_16x16x32_bf16(k0, qa[0][0], zero, 0, 0, 0);
      s1[kc] = __builtin_amdgcn_mfma_f32_16x16x32_bf16(k0, qa[1][0], zero, 0, 0, 0);
      s0[kc] = __builtin_amdgcn_mfma_f32_16x16x32_bf16(k1, qa[0][1], s0[kc], 0, 0, 0);
      s1[kc] = __builtin_amdgcn_mfma_f32_16x16x32_bf16(k1, qa[1][1], s1[kc], 0, 0, 0);
    }
    __builtin_amdgcn_s_setprio(0);

    // softmax; P packed straight into PV A-fragments (lane-local, q = mr)
    W8 paw[2][2];
    {
      float e[16];
      #pragma unroll
      for (int kc = 0; kc < 4; kc++)
        #pragma unroll
        for (int r = 0; r < 4; r++)
          e[kc * 4 + r] = fast_exp2(s0[kc][r]);
      paw[0][0].u[0] = f2b_pk(e[0], e[1]);
      paw[0][0].u[1] = f2b_pk(e[2], e[3]);
      paw[0][0].u[2] = f2b_pk(e[4], e[5]);
      paw[0][0].u[3] = f2b_pk(e[6], e[7]);
      paw[0][1].u[0] = f2b_pk(e[8], e[9]);
      paw[0][1].u[1] = f2b_pk(e[10], e[11]);
      paw[0][1].u[2] = f2b_pk(e[12], e[13]);
      paw[0][1].u[3] = f2b_pk(e[14], e[15]);
    }
    {
      float e[16];
      #pragma unroll
      for (int kc = 0; kc < 4; kc++)
        #pragma unroll
        for (int r = 0; r < 4; r++)
          e[kc * 4 + r] = fast_exp2(s1[kc][r]);
      paw[1][0].u[0] = f2b_pk(e[0], e[1]);
      paw[1][0].u[1] = f2b_pk(e[2], e[3]);
      paw[1][0].u[2] = f2b_pk(e[4], e[5]);
      paw[1][0].u[3] = f2b_pk(e[6], e[7]);
      paw[1][1].u[0] = f2b_pk(e[8], e[9]);
      paw[1][1].u[1] = f2b_pk(e[10], e[11]);
      paw[1][1].u[2] = f2b_pk(e[12], e[13]);
      paw[1][1].u[3] = f2b_pk(e[14], e[15]);
    }

    // row sums via MFMA against ones (D-layout identical to o)
    __builtin_amdgcn_s_setprio(1);
    lacc[0] = __builtin_amdgcn_mfma_f32_16x16x32_bf16(
        paw[0][0].v, ones, lacc[0], 0, 0, 0);
    lacc[0] = __builtin_amdgcn_mfma_f32_16x16x32_bf16(
        paw[0][1].v, ones, lacc[0], 0, 0, 0);
    lacc[1] = __builtin_amdgcn_mfma_f32_16x16x32_bf16(
        paw[1][0].v, ones, lacc[1], 0, 0, 0);
    lacc[1] = __builtin_amdgcn_mfma_f32_16x16x32_bf16(
        paw[1][1].v, ones, lacc[1], 0, 0, 0);
    __builtin_amdgcn_s_setprio(0);

    // PV: stream V fragments (one ni at a time, feeds both subs)
    #pragma unroll
    for (int ni = 0; ni < 4; ni++) {
      bf16x8 v0 = *(const bf16x8*)(Vs[cur] + (ni * 16 + mr) * 64 +
                                   ((quad ^ mr7) * 8));
      bf16x8 v1 = *(const bf16x8*)(Vs[cur] + (ni * 16 + mr) * 64 +
                                   (((4 + quad) ^ mr7) * 8));
      __builtin_amdgcn_s_setprio(1);
      o[0][ni] = __builtin_amdgcn_mfma_f32_16x16x32_bf16(
          paw[0][0].v, v0, o[0][ni], 0, 0, 0);
      o[1][ni] = __builtin_amdgcn_mfma_f32_16x16x32_bf16(
          paw[1][0].v, v0, o[1][ni], 0, 0, 0);
      o[0][ni] = __builtin_amdgcn_mfma_f32_16x16x32_bf16(
          paw[0][1].v, v1, o[0][ni], 0, 0, 0);
      o[1][ni] = __builtin_amdgcn_mfma_f32_16x16x32_bf16(
          paw[1][1].v, v1, o[1][ni], 0, 0, 0);
      __builtin_amdgcn_s_setprio(0);
    }

    __syncthreads();   // drains prefetch (covered by ~full tile of compute)
  }

  // epilogue: lacc[sub][r] is the row sum for q = quad*4+r (replicated over
  // the mr lanes) -- same layout as o. No shuffles.
  #pragma unroll
  for (int sub = 0; sub < 2; sub++) {
    #pragma unroll
    for (int r = 0; r < 4; r++) {
      float inv = 1.0f / lacc[sub][r];
      int qq = q0 + wave * 32 + sub * 16 + quad * 4 + r;
      #pragma unroll
      for (int ni = 0; ni < 4; ni++)
        O[headK + (size_t)qq * Dc + ni * 16 + mr] = f2b(o[sub][ni][r] * inv);
    }
  }
}

// ---------------------------------------------------------------------------
extern "C" void kernel_launch(void* const* d_in, const int* in_sizes, int n_in,
                              void* d_out, int out_size, void* d_ws, size_t ws_size,
                              hipStream_t stream) {
  const float* emb = (const float*)d_in[0];
  const float* Wq  = (const float*)d_in[1];
  const float* Wk  = (const float*)d_in[2];
  const float* Wv  = (const float*)d_in[3];
  const float* Wo  = (const float*)d_in[4];
  float* out = (float*)d_out;

  const int M = Bc * Sc;                   // 8192

  u16* Eb  = (u16*)d_ws;
  u16* Wqb = Eb  + EDc;
  u16* Wkb = Wqb + WDc;
  u16* Wvb = Wkb + WDc;
  u16* Wob = Wvb + WDc;
  u16* Qb  = Wob + WDc;
  u16* Kb  = Qb  + EDc;
  u16* VTb = Kb  + EDc;
  u16* Cb  = Qb;  // ctx overwrites Q (per-block same-slice read-then-write)

  dim3 blk(256);
  cvt_all<<<dim3(4096 + 4 * 512), blk, 0, stream>>>(emb, Wq, Wk, Wv, Wo, Eb);

  gemm_qkv<<<dim3(24, M / 128), blk, 0, stream>>>(Eb, Wqb, Wkb, Wvb,
                                                  Qb, Kb, VTb);

  attn<<<dim3(Sc / 256, Bc * Hc), dim3(512), 0, stream>>>(Qb, Kb, VTb, Cb);

  gemm_out<<<dim3(Dc / 128, M / 128), blk, 0, stream>>>(Cb, Wob, out,
                                                        M, Dc, Dc);
}

// Round 15
// 242.451 us; speedup vs baseline: 1.0698x; 1.0245x over previous
//
#include <hip/hip_runtime.h>
#include <hip/hip_bf16.h>

typedef unsigned short u16;
typedef __attribute__((ext_vector_type(8))) short bf16x8;
typedef __attribute__((ext_vector_type(4))) float f32x4;

#define AS1 __attribute__((address_space(1)))
#define AS3 __attribute__((address_space(3)))

constexpr int Bc = 4, Sc = 2048, Dc = 1024, Hc = 16, DKc = 64;
constexpr size_t EDc = (size_t)Bc * Sc * Dc;   // 8388608
constexpr size_t WDc = (size_t)Dc * Dc;        // 1048576

__device__ __forceinline__ void g2l16(const void* g, void* l) {
  __builtin_amdgcn_global_load_lds((const AS1 unsigned int*)g,
                                   (AS3 unsigned int*)l, 16, 0, 0);
}

// fp32 -> bf16 via native cast: hipcc emits HW v_cvt and fuses adjacent
// pairs into v_cvt_pk_bf16_f32 (round-14: replaced manual RTNE bit-twiddle
// fallback that cost ~320 VALU cyc/wave-tile; attn 93.6 -> 85.3 us).
__device__ __forceinline__ u16 f2b(float f) {
  union { __bf16 h; u16 u; } x;
  x.h = (__bf16)f;
  return x.u;
}

__device__ __forceinline__ unsigned f2b_pk(float a, float b) {
  union { __bf16 h[2]; unsigned u; } x;
  x.h[0] = (__bf16)a;
  x.h[1] = (__bf16)b;
  return x.u;
}

__device__ __forceinline__ float fast_exp2(float x) {
#if __has_builtin(__builtin_amdgcn_exp2f)
  return __builtin_amdgcn_exp2f(x);
#else
  return exp2f(x);
#endif
}

// ---------------------------------------------------------------------------
// Fused fp32->bf16 for all 5 inputs (dest regions contiguous in ws).
// ---------------------------------------------------------------------------
__global__ __launch_bounds__(256)
void cvt_all(const float* __restrict__ e, const float* __restrict__ wq,
             const float* __restrict__ wk, const float* __restrict__ wv,
             const float* __restrict__ wo, u16* __restrict__ dst) {
  int bx = blockIdx.x;
  const float* src;
  size_t doff;
  int chunk;
  if (bx < 4096) {
    src = e; doff = 0; chunk = bx;
  } else {
    int t = bx - 4096;
    int w = t >> 9;
    chunk = t & 511;
    src = (w == 0) ? wq : (w == 1) ? wk : (w == 2) ? wv : wo;
    doff = EDc + (size_t)w * WDc;
  }
  size_t i = ((size_t)chunk * 256 + threadIdx.x) * 8;
  float4 a = *(const float4*)(src + i);
  float4 b = *(const float4*)(src + i + 4);
  bf16x8 o;
  o[0] = (short)f2b(a.x); o[1] = (short)f2b(a.y);
  o[2] = (short)f2b(a.z); o[3] = (short)f2b(a.w);
  o[4] = (short)f2b(b.x); o[5] = (short)f2b(b.y);
  o[6] = (short)f2b(b.z); o[7] = (short)f2b(b.w);
  *(bf16x8*)(dst + doff + i) = o;
}

// ---------------------------------------------------------------------------
// Fused QKV GEMM (round-11 form -- session best; GEMM micro-structure proven
// insensitive over rounds 6/7/8/12 variants, occupancy-forcing refuted in
// rounds 5/12). sect 0 = Q (0.125*log2e folded), 1 = K, 2 = V
// (operand-swapped -> contiguous VT stores, within-64-key permutation
// pos(k): [h|b|qq|r] -> [h|qq|b|r] matching attn's register-resident P).
// XCD swizzle: each XCD owns 8 consecutive m-panels.
// ---------------------------------------------------------------------------
__global__ __launch_bounds__(256, 2)
void gemm_qkv(const u16* __restrict__ X, const u16* __restrict__ Wq,
              const u16* __restrict__ Wk, const u16* __restrict__ Wv,
              u16* __restrict__ Qo, u16* __restrict__ Ko,
              u16* __restrict__ VTo) {
  constexpr int BM = 128, BK = 64, K = Dc, N = Dc;
  __shared__ u16 As[BM * BK];
  __shared__ u16 Bs[BM * BK];

  const int tid = threadIdx.x;
  const int wave = tid >> 6, lane = tid & 63;
  const int mr = lane & 15, quad = lane >> 4, mr7 = lane & 7;
  const int hwlin = blockIdx.y * 24 + blockIdx.x;        // 1536 blocks
  const int swz = (hwlin & 7) * 192 + (hwlin >> 3);      // bijective
  const int lx = swz % 24, ly = swz / 24;
  const int sect = lx >> 3;
  const int n0 = (lx & 7) * 128;
  const int m0 = ly * BM;
  const u16* W = (sect == 0) ? Wq : (sect == 1) ? Wk : Wv;
  const int wm = (wave >> 1) * 64, wn = (wave & 1) * 64;
  const int ldr = lane >> 3;
  const int ldc_sw = ((lane & 7) ^ (ldr & 7)) * 8;
  const bool vsec = (sect == 2);

  const f32x4 zero = {0.f, 0.f, 0.f, 0.f};
  f32x4 acc[4][4];
  #pragma unroll
  for (int i = 0; i < 4; i++)
    #pragma unroll
    for (int j = 0; j < 4; j++) acc[i][j] = zero;

  for (int k0 = 0; k0 < K; k0 += BK) {
    __syncthreads();
    #pragma unroll
    for (int i = 0; i < 4; i++) {
      int row = wave * 32 + i * 8;
      g2l16(X + (size_t)(m0 + row + ldr) * K + k0 + ldc_sw, As + row * BK);
      g2l16(W + (size_t)(n0 + row + ldr) * K + k0 + ldc_sw, Bs + row * BK);
    }
    __syncthreads();

    #pragma unroll
    for (int c = 0; c < 2; c++) {
      bf16x8 a[4], b[4];
      #pragma unroll
      for (int i = 0; i < 4; i++)
        a[i] = *(const bf16x8*)(As + (wm + i * 16 + mr) * BK +
                                (((c * 4 + quad) ^ mr7) * 8));
      #pragma unroll
      for (int j = 0; j < 4; j++)
        b[j] = *(const bf16x8*)(Bs + (wn + j * 16 + mr) * BK +
                                (((c * 4 + quad) ^ mr7) * 8));
      if (vsec) {
        #pragma unroll
        for (int i = 0; i < 4; i++)
          #pragma unroll
          for (int j = 0; j < 4; j++)
            acc[i][j] = __builtin_amdgcn_mfma_f32_16x16x32_bf16(
                b[j], a[i], acc[i][j], 0, 0, 0);   // D = Y^T tile
      } else {
        #pragma unroll
        for (int i = 0; i < 4; i++)
          #pragma unroll
          for (int j = 0; j < 4; j++)
            acc[i][j] = __builtin_amdgcn_mfma_f32_16x16x32_bf16(
                a[i], b[j], acc[i][j], 0, 0, 0);
      }
    }
  }

  if (vsec) {
    #pragma unroll
    for (int i = 0; i < 4; i++) {
      int s_glob = m0 + wm + i * 16 + mr;
      int bb = s_glob >> 11, s = s_glob & 2047;
      int sp = (s & ~63) | (s & 32) | ((s & 12) << 1) | ((s & 16) >> 2) |
               (s & 3);
      #pragma unroll
      for (int j = 0; j < 4; j++) {
        int nbase = n0 + wn + j * 16 + quad * 4;
        #pragma unroll
        for (int r = 0; r < 4; r++) {
          int n = nbase + r;
          int h = n >> 6, d = n & 63;
          VTo[((size_t)((bb * Hc + h) * DKc + d)) * Sc + sp] = f2b(acc[i][j][r]);
        }
      }
    }
  } else {
    const float scale = (sect == 0) ? 0.18033688f : 1.0f;
    u16* Y = (sect == 0) ? Qo : Ko;
    #pragma unroll
    for (int i = 0; i < 4; i++)
      #pragma unroll
      for (int j = 0; j < 4; j++)
        #pragma unroll
        for (int r = 0; r < 4; r++) {
          int m = m0 + wm + i * 16 + quad * 4 + r;
          int n = n0 + wn + j * 16 + mr;
          Y[(size_t)m * N + n] = f2b(acc[i][j][r] * scale);
        }
  }
}

// ---------------------------------------------------------------------------
// Output GEMM: out = ctx @ Wo.T, fp32 output (round-11 form). XCD swizzle.
// ---------------------------------------------------------------------------
__global__ __launch_bounds__(256, 2)
void gemm_out(const u16* __restrict__ X, const u16* __restrict__ W,
              float* __restrict__ Y, int M, int N, int K) {
  constexpr int BM = 128, BK = 64;
  __shared__ u16 As[BM * BK];
  __shared__ u16 Bs[BM * BK];

  const int tid = threadIdx.x;
  const int wave = tid >> 6, lane = tid & 63;
  const int mr = lane & 15, quad = lane >> 4, mr7 = lane & 7;
  const int hwlin = blockIdx.y * 8 + blockIdx.x;        // 512 blocks
  const int swz = (hwlin & 7) * 64 + (hwlin >> 3);      // bijective
  const int m0 = (swz >> 3) * BM, n0 = (swz & 7) * BM;
  const int wm = (wave >> 1) * 64, wn = (wave & 1) * 64;
  const int ldr = lane >> 3;
  const int ldc_sw = ((lane & 7) ^ (ldr & 7)) * 8;

  const f32x4 zero = {0.f, 0.f, 0.f, 0.f};
  f32x4 acc[4][4];
  #pragma unroll
  for (int i = 0; i < 4; i++)
    #pragma unroll
    for (int j = 0; j < 4; j++) acc[i][j] = zero;

  for (int k0 = 0; k0 < K; k0 += BK) {
    __syncthreads();
    #pragma unroll
    for (int i = 0; i < 4; i++) {
      int row = wave * 32 + i * 8;
      g2l16(X + (size_t)(m0 + row + ldr) * K + k0 + ldc_sw, As + row * BK);
      g2l16(W + (size_t)(n0 + row + ldr) * K + k0 + ldc_sw, Bs + row * BK);
    }
    __syncthreads();

    #pragma unroll
    for (int c = 0; c < 2; c++) {
      bf16x8 a[4], b[4];
      #pragma unroll
      for (int i = 0; i < 4; i++)
        a[i] = *(const bf16x8*)(As + (wm + i * 16 + mr) * BK +
                                (((c * 4 + quad) ^ mr7) * 8));
      #pragma unroll
      for (int j = 0; j < 4; j++)
        b[j] = *(const bf16x8*)(Bs + (wn + j * 16 + mr) * BK +
                                (((c * 4 + quad) ^ mr7) * 8));
      #pragma unroll
      for (int i = 0; i < 4; i++)
        #pragma unroll
        for (int j = 0; j < 4; j++)
          acc[i][j] = __builtin_amdgcn_mfma_f32_16x16x32_bf16(
              a[i], b[j], acc[i][j], 0, 0, 0);
    }
  }

  #pragma unroll
  for (int i = 0; i < 4; i++)
    #pragma unroll
    for (int j = 0; j < 4; j++)
      #pragma unroll
      for (int r = 0; r < 4; r++) {
        int m = m0 + wm + i * 16 + quad * 4 + r;
        int n = n0 + wn + j * 16 + mr;
        Y[(size_t)m * N + n] = acc[i][j][r];
      }
}

// ---------------------------------------------------------------------------
// Flash attention (round-14 + kt-loop 2x unroll with compile-time buffer
// pointers). With cur static per half-body, all 16 ds_read_b128 addresses
// per tile are loop-invariant lane constants -- the compiler can hoist one
// base VGPR per buffer/matrix and fold the kc stride (2048 B) into the
// ds_read offset: immediate, removing per-iteration address VALU (the
// largest remaining non-essential VALU term; kernel is issue-bound at
// MfmaUtil 38 + VALUBusy 48).
// REGISTER-RESIDENT P via swapped QK^T + V-permutation; 8 waves x 32 q-rows;
// streamed K/V fragments; MFMA row-sums vs ones; XCD swizzle (K/V
// L2-resident); native-cast bf16 packing (v_cvt_pk).
// LDS: Ks 2x8K + Vs 2x8K = 32 KB.
// ---------------------------------------------------------------------------
__global__ __launch_bounds__(512, 4)
void attn(const u16* __restrict__ Q, const u16* __restrict__ K,
          const u16* __restrict__ VT, u16* __restrict__ O) {
  __shared__ u16 Ks[2][64 * 64];     // [buf][key row][d], XOR-swizzled cols
  __shared__ u16 Vs[2][64 * 64];     // [buf][d][key], XOR-swizzled cols

  const int tid = threadIdx.x;
  const int wave = tid >> 6, lane = tid & 63;
  const int mr = lane & 15, quad = lane >> 4, mr7 = lane & 7;
  // XCD swizzle: XCD c gets heads [c*8, c*8+8) -> K/V L2-resident.
  const int hwlin = blockIdx.y * 8 + blockIdx.x;      // 512 blocks
  const int swz = (hwlin & 7) * 64 + (hwlin >> 3);    // bijective
  const int bh = swz >> 3;
  const int q0 = (swz & 7) * 256;
  const int b = bh >> 4, h = bh & 15;
  const size_t headK = (size_t)b * Sc * Dc + (size_t)h * DKc;
  const size_t headV = (size_t)bh * DKc * Sc;
  const int ldr = lane >> 3;
  const int ldc_sw = ((lane & 7) ^ (ldr & 7)) * 8;

  // per-wave staging rows: 8 waves x 8 rows = 64 rows per buffer
  const int row0 = wave * 8;
  const int pr = row0 + ldr;

  // Q fragments: 2 subtiles x 2 k-chunks (0.125*log2e folded into Q GEMM).
  bf16x8 qa[2][2];
  #pragma unroll
  for (int sub = 0; sub < 2; sub++)
    #pragma unroll
    for (int c = 0; c < 2; c++)
      qa[sub][c] = *(const bf16x8*)(Q + headK +
          (size_t)(q0 + wave * 32 + sub * 16 + mr) * Dc + c * 32 + quad * 8);

  const f32x4 zero = {0.f, 0.f, 0.f, 0.f};
  const short one_bf = (short)0x3F80;   // bf16 1.0
  const bf16x8 ones = {one_bf, one_bf, one_bf, one_bf,
                       one_bf, one_bf, one_bf, one_bf};
  f32x4 o[2][4];
  f32x4 lacc[2];
  #pragma unroll
  for (int sub = 0; sub < 2; sub++) {
    lacc[sub] = zero;
    #pragma unroll
    for (int i = 0; i < 4; i++) o[sub][i] = zero;
  }

  // lane-constant LDS offsets (elements)
  const int koff0 = mr * 64 + ((quad ^ mr7) * 8);
  const int koff1 = mr * 64 + (((4 + quad) ^ mr7) * 8);

  // stage tile 0 into buf 0 (K rows natural; V already column-permuted)
  g2l16(K + headK + (size_t)pr * Dc + ldc_sw, Ks[0] + row0 * 64);
  g2l16(VT + headV + (size_t)pr * Sc + ldc_sw, Vs[0] + row0 * 64);
  __syncthreads();

  union W8 { unsigned u[4]; bf16x8 v; };

  // body with compile-time-constant buffer pointers (cur static per call):
  // all ds_read addresses are loop-invariant; kc stride folds to offset:.
  auto body = [&](int kt, const u16* __restrict__ Kb, const u16* __restrict__ Vb,
                  u16* __restrict__ Kn, u16* __restrict__ Vn) {
    if (kt + 1 < Sc / 64) {
      const int nk0 = (kt + 1) * 64;
      g2l16(K + headK + (size_t)(nk0 + pr) * Dc + ldc_sw, Kn + row0 * 64);
      g2l16(VT + headV + (size_t)pr * Sc + nk0 + ldc_sw, Vn + row0 * 64);
    }

    // swapped QK^T: stream K fragments (one kc at a time, feeds both subs)
    f32x4 s0[4], s1[4];
    __builtin_amdgcn_s_setprio(1);
    #pragma unroll
    for (int kc = 0; kc < 4; kc++) {
      bf16x8 k0 = *(const bf16x8*)(Kb + kc * 1024 + koff0);
      bf16x8 k1 = *(const bf16x8*)(Kb + kc * 1024 + koff1);
      s0[kc] = __builtin_amdgcn_mfma_f32_16x16x32_bf16(k0, qa[0][0], zero, 0, 0, 0);
      s1[kc] = __builtin_amdgcn_mfma_f32_16x16x32_bf16(k0, qa[1][0], zero, 0, 0, 0);
      s0[kc] = __builtin_amdgcn_mfma_f32_16x16x32_bf16(k1, qa[0][1], s0[kc], 0, 0, 0);
      s1[kc] = __builtin_amdgcn_mfma_f32_16x16x32_bf16(k1, qa[1][1], s1[kc], 0, 0, 0);
    }
    __builtin_amdgcn_s_setprio(0);

    // softmax; P packed straight into PV A-fragments (lane-local, q = mr)
    W8 paw[2][2];
    {
      float e[16];
      #pragma unroll
      for (int kc = 0; kc < 4; kc++)
        #pragma unroll
        for (int r = 0; r < 4; r++)
          e[kc * 4 + r] = fast_exp2(s0[kc][r]);
      paw[0][0].u[0] = f2b_pk(e[0], e[1]);
      paw[0][0].u[1] = f2b_pk(e[2], e[3]);
      paw[0][0].u[2] = f2b_pk(e[4], e[5]);
      paw[0][0].u[3] = f2b_pk(e[6], e[7]);
      paw[0][1].u[0] = f2b_pk(e[8], e[9]);
      paw[0][1].u[1] = f2b_pk(e[10], e[11]);
      paw[0][1].u[2] = f2b_pk(e[12], e[13]);
      paw[0][1].u[3] = f2b_pk(e[14], e[15]);
    }
    {
      float e[16];
      #pragma unroll
      for (int kc = 0; kc < 4; kc++)
        #pragma unroll
        for (int r = 0; r < 4; r++)
          e[kc * 4 + r] = fast_exp2(s1[kc][r]);
      paw[1][0].u[0] = f2b_pk(e[0], e[1]);
      paw[1][0].u[1] = f2b_pk(e[2], e[3]);
      paw[1][0].u[2] = f2b_pk(e[4], e[5]);
      paw[1][0].u[3] = f2b_pk(e[6], e[7]);
      paw[1][1].u[0] = f2b_pk(e[8], e[9]);
      paw[1][1].u[1] = f2b_pk(e[10], e[11]);
      paw[1][1].u[2] = f2b_pk(e[12], e[13]);
      paw[1][1].u[3] = f2b_pk(e[14], e[15]);
    }

    // row sums via MFMA against ones (D-layout identical to o)
    __builtin_amdgcn_s_setprio(1);
    lacc[0] = __builtin_amdgcn_mfma_f32_16x16x32_bf16(
        paw[0][0].v, ones, lacc[0], 0, 0, 0);
    lacc[0] = __builtin_amdgcn_mfma_f32_16x16x32_bf16(
        paw[0][1].v, ones, lacc[0], 0, 0, 0);
    lacc[1] = __builtin_amdgcn_mfma_f32_16x16x32_bf16(
        paw[1][0].v, ones, lacc[1], 0, 0, 0);
    lacc[1] = __builtin_amdgcn_mfma_f32_16x16x32_bf16(
        paw[1][1].v, ones, lacc[1], 0, 0, 0);
    __builtin_amdgcn_s_setprio(0);

    // PV: stream V fragments (one ni at a time, feeds both subs)
    #pragma unroll
    for (int ni = 0; ni < 4; ni++) {
      bf16x8 v0 = *(const bf16x8*)(Vb + ni * 1024 + koff0);
      bf16x8 v1 = *(const bf16x8*)(Vb + ni * 1024 + koff1);
      __builtin_amdgcn_s_setprio(1);
      o[0][ni] = __builtin_amdgcn_mfma_f32_16x16x32_bf16(
          paw[0][0].v, v0, o[0][ni], 0, 0, 0);
      o[1][ni] = __builtin_amdgcn_mfma_f32_16x16x32_bf16(
          paw[1][0].v, v0, o[1][ni], 0, 0, 0);
      o[0][ni] = __builtin_amdgcn_mfma_f32_16x16x32_bf16(
          paw[0][1].v, v1, o[0][ni], 0, 0, 0);
      o[1][ni] = __builtin_amdgcn_mfma_f32_16x16x32_bf16(
          paw[1][1].v, v1, o[1][ni], 0, 0, 0);
      __builtin_amdgcn_s_setprio(0);
    }

    __syncthreads();   // drains prefetch (covered by ~full tile of compute)
  };

  for (int kt = 0; kt < Sc / 64; kt += 2) {
    body(kt,     Ks[0], Vs[0], Ks[1], Vs[1]);
    body(kt + 1, Ks[1], Vs[1], Ks[0], Vs[0]);
  }

  // epilogue: lacc[sub][r] is the row sum for q = quad*4+r (replicated over
  // the mr lanes) -- same layout as o. No shuffles.
  #pragma unroll
  for (int sub = 0; sub < 2; sub++) {
    #pragma unroll
    for (int r = 0; r < 4; r++) {
      float inv = 1.0f / lacc[sub][r];
      int qq = q0 + wave * 32 + sub * 16 + quad * 4 + r;
      #pragma unroll
      for (int ni = 0; ni < 4; ni++)
        O[headK + (size_t)qq * Dc + ni * 16 + mr] = f2b(o[sub][ni][r] * inv);
    }
  }
}

// ---------------------------------------------------------------------------
extern "C" void kernel_launch(void* const* d_in, const int* in_sizes, int n_in,
                              void* d_out, int out_size, void* d_ws, size_t ws_size,
                              hipStream_t stream) {
  const float* emb = (const float*)d_in[0];
  const float* Wq  = (const float*)d_in[1];
  const float* Wk  = (const float*)d_in[2];
  const float* Wv  = (const float*)d_in[3];
  const float* Wo  = (const float*)d_in[4];
  float* out = (float*)d_out;

  const int M = Bc * Sc;                   // 8192

  u16* Eb  = (u16*)d_ws;
  u16* Wqb = Eb  + EDc;
  u16* Wkb = Wqb + WDc;
  u16* Wvb = Wkb + WDc;
  u16* Wob = Wvb + WDc;
  u16* Qb  = Wob + WDc;
  u16* Kb  = Qb  + EDc;
  u16* VTb = Kb  + EDc;
  u16* Cb  = Qb;  // ctx overwrites Q (per-block same-slice read-then-write)

  dim3 blk(256);
  cvt_all<<<dim3(4096 + 4 * 512), blk, 0, stream>>>(emb, Wq, Wk, Wv, Wo, Eb);

  gemm_qkv<<<dim3(24, M / 128), blk, 0, stream>>>(Eb, Wqb, Wkb, Wvb,
                                                  Qb, Kb, VTb);

  attn<<<dim3(Sc / 256, Bc * Hc), dim3(512), 0, stream>>>(Qb, Kb, VTb, Cb);

  gemm_out<<<dim3(Dc / 128, M / 128), blk, 0, stream>>>(Cb, Wob, out,
                                                        M, Dc, Dc);
}